// Round 7
// baseline (235.711 us; speedup 1.0000x reference)
//
#include <hip/hip_runtime.h>

#define HW  262144     // 512*512
#define HW4 65536      // HW/4
#define NPATCH 16384   // 16 * 32 * 32

// ws layout (floats):
// [0]                : exposure sum of (patch_mean - E)^2
// [1]                : tv vertical sum
// [2]                : tv horizontal sum
// [3 .. 51)          : color channel sums, index 3 + b*3 + c   (48)
// [51 .. 51+128*11)  : semantic stats, index 51 + (b*8+k)*11 + s
//                      s: 0=sumM 1=sumM2 2..4=sRM[c] 5..7=sRM2[c] 8..10=sR2M2[c]
#define WS_FLOATS (3 + 48 + 128*11)

#define SEM_BLOCKS   2048
#define L_BLOCKS     512
#define COLOR_BLOCKS 768
#define TOTAL_BLOCKS (SEM_BLOCKS + L_BLOCKS + COLOR_BLOCKS)

typedef float nfloat4 __attribute__((ext_vector_type(4)));

__device__ __forceinline__ float wave_reduce(float x) {
#pragma unroll
  for (int o = 32; o >= 1; o >>= 1) x += __shfl_down(x, o);
  return x;
}

// non-temporal float4 load (evict-first hint; read-once streams)
__device__ __forceinline__ float4 ntload4(const float4* p) {
  nfloat4 v = __builtin_nontemporal_load((const nfloat4*)p);
  return make_float4(v.x, v.y, v.z, v.w);
}

// 11 named scalar accumulators per k (no arrays -> no scratch demotion)
#define SEM_ACC(P)                                                             \
  float P##n = 0.f, P##n2 = 0.f, P##p0 = 0.f, P##p1 = 0.f, P##p2 = 0.f,       \
        P##q0 = 0.f, P##q1 = 0.f, P##q2 = 0.f, P##r0 = 0.f, P##r1 = 0.f,      \
        P##r2 = 0.f;

// per-element update for one k; x0..x2, xx0..xx2 from enclosing scope
#define SEM_K(P, mm)                                                           \
  {                                                                            \
    float _m = (mm), _m2 = _m * _m;                                            \
    P##n += _m;                                                                \
    P##n2 += _m2;                                                              \
    P##p0 += x0 * _m;  P##p1 += x1 * _m;  P##p2 += x2 * _m;                    \
    P##q0 += x0 * _m2; P##q1 += x1 * _m2; P##q2 += x2 * _m2;                   \
    P##r0 += xx0 * _m2; P##r1 += xx1 * _m2; P##r2 += xx2 * _m2;                \
  }

// one float4 element e across the wave's 4 k-slices
#define DO_E(e)                                                                \
  {                                                                            \
    float x0 = r0.e, x1 = r1.e, x2 = r2.e;                                     \
    float xx0 = x0 * x0, xx1 = x1 * x1, xx2 = x2 * x2;                         \
    SEM_K(Ka, m0.e) SEM_K(Kb, m1.e) SEM_K(Kc, m2.e) SEM_K(Kd, m3.e)            \
  }

#define SEM_OUT(P, kk)                                                         \
  {                                                                            \
    float* dst = ws + 51 + (size_t)((b * 8 + (kk)) * 11);                      \
    float v;                                                                   \
    v = wave_reduce(P##n);   if (lane == 0) atomicAdd(&dst[0], v);             \
    v = wave_reduce(P##n2);  if (lane == 0) atomicAdd(&dst[1], v);             \
    v = wave_reduce(P##p0);  if (lane == 0) atomicAdd(&dst[2], v);             \
    v = wave_reduce(P##p1);  if (lane == 0) atomicAdd(&dst[3], v);             \
    v = wave_reduce(P##p2);  if (lane == 0) atomicAdd(&dst[4], v);             \
    v = wave_reduce(P##q0);  if (lane == 0) atomicAdd(&dst[5], v);             \
    v = wave_reduce(P##q1);  if (lane == 0) atomicAdd(&dst[6], v);             \
    v = wave_reduce(P##q2);  if (lane == 0) atomicAdd(&dst[7], v);             \
    v = wave_reduce(P##r0);  if (lane == 0) atomicAdd(&dst[8], v);             \
    v = wave_reduce(P##r1);  if (lane == 0) atomicAdd(&dst[9], v);             \
    v = wave_reduce(P##r2);  if (lane == 0) atomicAdd(&dst[10], v);            \
  }

__global__ __launch_bounds__(256) void mega_kernel(
    const float* __restrict__ L, const float* __restrict__ R,
    const float* __restrict__ I, const float* __restrict__ M,
    float* __restrict__ ws) {
  const int bid = blockIdx.x;
  const int tid = threadIdx.x;
  const int lane = tid & 63;

  if (bid < SEM_BLOCKS) {
    // ---------------- semantic stats: R (B,3,H,W) x M (B,8,H,W) ------------
    // wave = (k-half, pixel-half): 4 k's x 4 iterations each; R read 2x/block.
    const int b = bid >> 7;            // 0..15
    const int xb = bid & 127;          // 0..127
    const int wv = tid >> 6;
    const int k0 = (wv & 1) * 4;       // 0 or 4
    const int phalf = wv >> 1;         // 0 or 1
    const float4* R4 = (const float4*)(R + (size_t)b * 3 * HW);
    const float4* M4 = (const float4*)(M + (size_t)b * 8 * HW);
    SEM_ACC(Ka) SEM_ACC(Kb) SEM_ACC(Kc) SEM_ACC(Kd)
    int i = xb * 64 + lane + phalf * 32768;
#pragma unroll
    for (int it = 0; it < 4; ++it, i += 8192) {
      float4 r0 = ntload4(&R4[i]);
      float4 r1 = ntload4(&R4[i + HW4]);
      float4 r2 = ntload4(&R4[i + 2 * HW4]);
      float4 m0 = ntload4(&M4[i + (k0 + 0) * HW4]);
      float4 m1 = ntload4(&M4[i + (k0 + 1) * HW4]);
      float4 m2 = ntload4(&M4[i + (k0 + 2) * HW4]);
      float4 m3 = ntload4(&M4[i + (k0 + 3) * HW4]);
      DO_E(x) DO_E(y) DO_E(z) DO_E(w)
    }
    SEM_OUT(Ka, k0 + 0)
    SEM_OUT(Kb, k0 + 1)
    SEM_OUT(Kc, k0 + 2)
    SEM_OUT(Kd, k0 + 3)
    return;
  }

  if (bid < SEM_BLOCKS + L_BLOCKS) {
    // ---------------- L band: TV (v+h) + exposure patches ------------------
    const int band = bid - SEM_BLOCKS;      // 0..511
    const int b = band >> 5;                // 0..15
    const int pr = band & 31;               // patch row 0..31
    const int half = tid >> 7;              // 0..1
    const int c4 = tid & 127;               // f4 column 0..127
    const int row0 = pr * 16 + half * 8;
    const float* Lb = L + (size_t)b * HW;
    const float4* L4b = (const float4*)Lb;
    __shared__ float part[2][128];
    __shared__ float redv[4], redh[4];

    float sv = 0.f, sh = 0.f, ps = 0.f;
    float4 cur = L4b[row0 * 128 + c4];
#pragma unroll
    for (int r = 0; r < 8; ++r) {
      sh += fabsf(cur.x - cur.y) + fabsf(cur.y - cur.z) + fabsf(cur.z - cur.w);
      float nx = __shfl_down(cur.x, 1);  // next f4's .x, same row
      if (lane == 63 && c4 < 127) nx = Lb[(row0 + r) * 512 + c4 * 4 + 4];
      if (c4 < 127) sh += fabsf(cur.w - nx);
      ps += (cur.x + cur.y) + (cur.z + cur.w);
      int nr = row0 + r + 1;
      if (nr < 512) {
        float4 nxt = L4b[nr * 128 + c4];
        sv += fabsf(cur.x - nxt.x) + fabsf(cur.y - nxt.y) +
              fabsf(cur.z - nxt.z) + fabsf(cur.w - nxt.w);
        cur = nxt;
      }
    }
    part[half][c4] = ps;
    sv = wave_reduce(sv);
    sh = wave_reduce(sh);
    int wv = tid >> 6;
    if (lane == 0) { redv[wv] = sv; redh[wv] = sh; }
    __syncthreads();
    if (tid == 0) {
      atomicAdd(&ws[1], (redv[0] + redv[1]) + (redv[2] + redv[3]));
      atomicAdd(&ws[2], (redh[0] + redh[1]) + (redh[2] + redh[3]));
    }
    float e = 0.f;
    if (tid < 32) {  // patch p = tid covers f4 cols [4p, 4p+4)
      float s = 0.f;
#pragma unroll
      for (int h = 0; h < 2; ++h)
#pragma unroll
        for (int q = 0; q < 4; ++q) s += part[h][tid * 4 + q];
      float d = s * (1.0f / 256.0f) - 0.6f;
      e = d * d;
    }
    e = wave_reduce(e);
    if (tid == 0) atomicAdd(&ws[0], e);
    return;
  }

  {
    // ---------------- color: per (b,c) channel sums of I_enh ---------------
    const int cid = bid - (SEM_BLOCKS + L_BLOCKS);  // 0..767
    const int slice = cid >> 4;             // 0..47
    const int xb = cid & 15;
    const float4* I4 = (const float4*)(I + (size_t)slice * HW);
    float s = 0.f;
    int i = xb * 256 + tid;
#pragma unroll 4
    for (int it = 0; it < 16; ++it, i += 4096) {
      float4 v = ntload4(&I4[i]);
      s += (v.x + v.y) + (v.z + v.w);
    }
    s = wave_reduce(s);
    __shared__ float red[4];
    int wv = tid >> 6;
    if (lane == 0) red[wv] = s;
    __syncthreads();
    if (tid == 0)
      atomicAdd(&ws[3 + slice], (red[0] + red[1]) + (red[2] + red[3]));
  }
}

// ---------------- final combine ----------------
__global__ __launch_bounds__(256) void final_kernel(const float* __restrict__ ws,
                                                    float* __restrict__ out) {
  __shared__ float red[256];
  int t = threadIdx.x;
  float sem = 0.f;
  if (t < 128) {
    const float* s = ws + 51 + t * 11;
    float n = s[0] + 1e-6f;
    float v = 0.f;
#pragma unroll
    for (int c = 0; c < 3; ++c) {
      float mean = s[2 + c] / n;
      v += s[8 + c] - 2.0f * mean * s[5 + c] + mean * mean * s[1];
    }
    sem = v / n;
  }
  red[t] = sem;
  __syncthreads();
  for (int s = 128; s > 0; s >>= 1) {
    if (t < s) red[t] += red[t + s];
    __syncthreads();
  }
  if (t == 0) {
    float L_sem = red[0] / 16.0f;
    float L_exp = ws[0] / (float)NPATCH;
    float L_tv = ws[1] / (16.0f * 511.0f * 512.0f) +
                 ws[2] / (16.0f * 512.0f * 511.0f);
    float L_color = 0.f;
#pragma unroll
    for (int b = 0; b < 16; ++b) {
      float r = ws[3 + b * 3 + 0] * (1.0f / (float)HW);
      float g = ws[3 + b * 3 + 1] * (1.0f / (float)HW);
      float bl = ws[3 + b * 3 + 2] * (1.0f / (float)HW);
      L_color += (r - g) * (r - g) + (r - bl) * (r - bl) + (g - bl) * (g - bl);
    }
    L_color *= (1.0f / 16.0f);
    out[0] = 10.0f * L_exp + 1.0f * L_tv + 10.0f * L_color + 50.0f * L_sem;
  }
}

extern "C" void kernel_launch(void* const* d_in, const int* in_sizes, int n_in,
                              void* d_out, int out_size, void* d_ws, size_t ws_size,
                              hipStream_t stream) {
  const float* L     = (const float*)d_in[0];  // (16,1,512,512)
  const float* R     = (const float*)d_in[1];  // (16,3,512,512)
  const float* I_enh = (const float*)d_in[2];  // (16,3,512,512)
  const float* M     = (const float*)d_in[3];  // (16,8,512,512)
  float* out = (float*)d_out;
  float* ws  = (float*)d_ws;

  (void)hipMemsetAsync(d_ws, 0, WS_FLOATS * sizeof(float), stream);
  mega_kernel<<<TOTAL_BLOCKS, 256, 0, stream>>>(L, R, I_enh, M, ws);
  final_kernel<<<1, 256, 0, stream>>>(ws, out);
}

// Round 8
// 71.248 us; speedup vs baseline: 3.3083x; 3.3083x over previous
//
#include <hip/hip_runtime.h>

#define HW  262144     // 512*512
#define HW4 65536      // HW/4
#define NPATCH 16384   // 16 * 32 * 32

// ws layout (floats):
// [0]                : exposure sum of (patch_mean - E)^2
// [1]                : tv vertical sum
// [2]                : tv horizontal sum
// [3 .. 51)          : color channel sums, index 3 + b*3 + c   (48)
// [51 .. 51+128*11)  : semantic stats, index 51 + (b*8+k)*11 + s
//                      s: 0=sumM 1=sumM2 2..4=sRM[c] 5..7=sRM2[c] 8..10=sR2M2[c]
#define WS_FLOATS (3 + 48 + 128*11)

// all blocks are 512 threads
#define SEM_BLOCKS   512    // 16 images x 32 blocks; each block: 2 windows of 1024 f4
#define LBAND_BLOCKS 256    // 2 bands per block
#define COLOR_BLOCKS 384
#define TOTAL_BLOCKS (SEM_BLOCKS + LBAND_BLOCKS + COLOR_BLOCKS)

__device__ __forceinline__ float wave_reduce(float x) {
#pragma unroll
  for (int o = 32; o >= 1; o >>= 1) x += __shfl_down(x, o);
  return x;
}

// one element update, single k; t-form: t=x*m -> p+=t, q+=t*m, r+=t*t
#define CEL(x0v, x1v, x2v, mmv)                                                \
  {                                                                            \
    float _m = (mmv), _m2 = _m * _m;                                           \
    float _t0 = (x0v) * _m, _t1 = (x1v) * _m, _t2 = (x2v) * _m;                \
    an += _m;  an2 += _m2;                                                     \
    ap0 += _t0;  ap1 += _t1;  ap2 += _t2;                                      \
    aq0 += _t0 * _m; aq1 += _t1 * _m; aq2 += _t2 * _m;                         \
    ar0 += _t0 * _t0; ar1 += _t1 * _t1; ar2 += _t2 * _t2;                      \
  }

__global__ __launch_bounds__(512) void mega_kernel(
    const float* __restrict__ L, const float* __restrict__ R,
    const float* __restrict__ I, const float* __restrict__ M,
    float* __restrict__ ws) {
  const int bid = blockIdx.x;
  const int tid = threadIdx.x;
  const int lane = tid & 63;

  if (bid < SEM_BLOCKS) {
    // ------------- semantic stats: R (B,3,H,W) x M (B,8,H,W) ---------------
    // Stream-per-wave topology: wave wv owns mask channel k=wv and reads its
    // M plane CONTIGUOUSLY (one stream per wave, prefetch-friendly). R is
    // staged once per block into LDS (1024-f4 window x 3 planes = 48 KB) and
    // consumed from LDS by all 8 waves. Wave k walks the window's 16 chunks
    // rotated by 2k to decorrelate L2 channels across waves.
    const int b = bid >> 5;            // 0..15
    const int wb = bid & 31;           // 0..31 -> windows 2wb, 2wb+1
    const int wv = tid >> 6;           // 0..7 == k
    const float4* R4 = (const float4*)(R + (size_t)b * 3 * HW);
    const float4* M4k = (const float4*)(M + ((size_t)b * 8 + wv) * HW);
    __shared__ float4 rl[3072];        // [plane][1024]

    float an = 0.f, an2 = 0.f, ap0 = 0.f, ap1 = 0.f, ap2 = 0.f;
    float aq0 = 0.f, aq1 = 0.f, aq2 = 0.f, ar0 = 0.f, ar1 = 0.f, ar2 = 0.f;

    for (int w2 = 0; w2 < 2; ++w2) {
      const int base = (wb * 2 + w2) * 1024;  // window start (f4 units)
      // stage R window: 3072 f4 by 512 threads = 6 each (coalesced)
#pragma unroll
      for (int r = 0; r < 6; ++r) {
        int j = tid + r * 512;
        rl[j] = R4[(j >> 10) * HW4 + base + (j & 1023)];
      }
      __syncthreads();
      // consume: wave wv reads its M plane chunk-rotated
#pragma unroll 4
      for (int c = 0; c < 16; ++c) {
        int o = (((c + 2 * wv) & 15) << 6) + lane;
        float4 m = M4k[base + o];
        float4 r0 = rl[o], r1 = rl[1024 + o], r2 = rl[2048 + o];
        CEL(r0.x, r1.x, r2.x, m.x)
        CEL(r0.y, r1.y, r2.y, m.y)
        CEL(r0.z, r1.z, r2.z, m.z)
        CEL(r0.w, r1.w, r2.w, m.w)
      }
      __syncthreads();  // protect LDS before next stage
    }

    float* dst = ws + 51 + (size_t)((b * 8 + wv) * 11);
    float v;
    v = wave_reduce(an);  if (lane == 0) atomicAdd(&dst[0], v);
    v = wave_reduce(an2); if (lane == 0) atomicAdd(&dst[1], v);
    v = wave_reduce(ap0); if (lane == 0) atomicAdd(&dst[2], v);
    v = wave_reduce(ap1); if (lane == 0) atomicAdd(&dst[3], v);
    v = wave_reduce(ap2); if (lane == 0) atomicAdd(&dst[4], v);
    v = wave_reduce(aq0); if (lane == 0) atomicAdd(&dst[5], v);
    v = wave_reduce(aq1); if (lane == 0) atomicAdd(&dst[6], v);
    v = wave_reduce(aq2); if (lane == 0) atomicAdd(&dst[7], v);
    v = wave_reduce(ar0); if (lane == 0) atomicAdd(&dst[8], v);
    v = wave_reduce(ar1); if (lane == 0) atomicAdd(&dst[9], v);
    v = wave_reduce(ar2); if (lane == 0) atomicAdd(&dst[10], v);
    return;
  }

  if (bid < SEM_BLOCKS + LBAND_BLOCKS) {
    // ------------- L bands: TV (v+h) + exposure; 2 bands per block ---------
    const int lidx = bid - SEM_BLOCKS;      // 0..255
    const int sub = tid >> 8;               // 0/1 -> band
    const int stid = tid & 255;
    const int band = lidx * 2 + sub;        // 0..511
    const int b = band >> 5;                // 0..15
    const int pr = band & 31;               // patch row
    const int half = stid >> 7;             // 0..1
    const int c4 = stid & 127;              // f4 column
    const int row0 = pr * 16 + half * 8;
    const float* Lb = L + (size_t)b * HW;
    const float4* L4b = (const float4*)Lb;
    __shared__ float part[2][2][128];
    __shared__ float redv[2][4], redh[2][4];

    float sv = 0.f, sh = 0.f, ps = 0.f;
    float4 cur = L4b[row0 * 128 + c4];
#pragma unroll
    for (int r = 0; r < 8; ++r) {
      sh += fabsf(cur.x - cur.y) + fabsf(cur.y - cur.z) + fabsf(cur.z - cur.w);
      float nx = __shfl_down(cur.x, 1);  // next f4's .x, same row
      if (lane == 63 && c4 < 127) nx = Lb[(row0 + r) * 512 + c4 * 4 + 4];
      if (c4 < 127) sh += fabsf(cur.w - nx);
      ps += (cur.x + cur.y) + (cur.z + cur.w);
      int nr = row0 + r + 1;
      if (nr < 512) {
        float4 nxt = L4b[nr * 128 + c4];
        sv += fabsf(cur.x - nxt.x) + fabsf(cur.y - nxt.y) +
              fabsf(cur.z - nxt.z) + fabsf(cur.w - nxt.w);
        cur = nxt;
      }
    }
    part[sub][half][c4] = ps;
    sv = wave_reduce(sv);
    sh = wave_reduce(sh);
    int wv2 = stid >> 6;  // wave within sub-block: 0..3
    if (lane == 0) { redv[sub][wv2] = sv; redh[sub][wv2] = sh; }
    __syncthreads();
    if (stid == 0) {
      atomicAdd(&ws[1],
                (redv[sub][0] + redv[sub][1]) + (redv[sub][2] + redv[sub][3]));
      atomicAdd(&ws[2],
                (redh[sub][0] + redh[sub][1]) + (redh[sub][2] + redh[sub][3]));
    }
    float e = 0.f;
    if (stid < 32) {  // patch p = stid covers f4 cols [4p, 4p+4)
      float s = 0.f;
#pragma unroll
      for (int h = 0; h < 2; ++h)
#pragma unroll
        for (int q = 0; q < 4; ++q) s += part[sub][h][stid * 4 + q];
      float d = s * (1.0f / 256.0f) - 0.6f;
      e = d * d;
    }
    e = wave_reduce(e);
    if (stid == 0) atomicAdd(&ws[0], e);
    return;
  }

  {
    // ------------- color: per (b,c) channel sums of I_enh ------------------
    const int cid = bid - (SEM_BLOCKS + LBAND_BLOCKS);  // 0..383
    const int slice = cid >> 3;             // 0..47
    const int xb8 = cid & 7;
    const float4* I4 = (const float4*)(I + (size_t)slice * HW);
    float s = 0.f;
    int i = xb8 * 8192 + tid;
#pragma unroll 4
    for (int it = 0; it < 16; ++it, i += 512) {
      float4 v = I4[i];
      s += (v.x + v.y) + (v.z + v.w);
    }
    s = wave_reduce(s);
    __shared__ float red[8];
    int wv = tid >> 6;
    if (lane == 0) red[wv] = s;
    __syncthreads();
    if (tid == 0) {
      float t = ((red[0] + red[1]) + (red[2] + red[3])) +
                ((red[4] + red[5]) + (red[6] + red[7]));
      atomicAdd(&ws[3 + slice], t);
    }
  }
}

// ---------------- final combine ----------------
__global__ __launch_bounds__(256) void final_kernel(const float* __restrict__ ws,
                                                    float* __restrict__ out) {
  __shared__ float red[256];
  int t = threadIdx.x;
  float sem = 0.f;
  if (t < 128) {
    const float* s = ws + 51 + t * 11;
    float n = s[0] + 1e-6f;
    float v = 0.f;
#pragma unroll
    for (int c = 0; c < 3; ++c) {
      float mean = s[2 + c] / n;
      v += s[8 + c] - 2.0f * mean * s[5 + c] + mean * mean * s[1];
    }
    sem = v / n;
  }
  red[t] = sem;
  __syncthreads();
  for (int s = 128; s > 0; s >>= 1) {
    if (t < s) red[t] += red[t + s];
    __syncthreads();
  }
  if (t == 0) {
    float L_sem = red[0] / 16.0f;
    float L_exp = ws[0] / (float)NPATCH;
    float L_tv = ws[1] / (16.0f * 511.0f * 512.0f) +
                 ws[2] / (16.0f * 512.0f * 511.0f);
    float L_color = 0.f;
#pragma unroll
    for (int b = 0; b < 16; ++b) {
      float r = ws[3 + b * 3 + 0] * (1.0f / (float)HW);
      float g = ws[3 + b * 3 + 1] * (1.0f / (float)HW);
      float bl = ws[3 + b * 3 + 2] * (1.0f / (float)HW);
      L_color += (r - g) * (r - g) + (r - bl) * (r - bl) + (g - bl) * (g - bl);
    }
    L_color *= (1.0f / 16.0f);
    out[0] = 10.0f * L_exp + 1.0f * L_tv + 10.0f * L_color + 50.0f * L_sem;
  }
}

extern "C" void kernel_launch(void* const* d_in, const int* in_sizes, int n_in,
                              void* d_out, int out_size, void* d_ws, size_t ws_size,
                              hipStream_t stream) {
  const float* L     = (const float*)d_in[0];  // (16,1,512,512)
  const float* R     = (const float*)d_in[1];  // (16,3,512,512)
  const float* I_enh = (const float*)d_in[2];  // (16,3,512,512)
  const float* M     = (const float*)d_in[3];  // (16,8,512,512)
  float* out = (float*)d_out;
  float* ws  = (float*)d_ws;

  (void)hipMemsetAsync(d_ws, 0, WS_FLOATS * sizeof(float), stream);
  mega_kernel<<<TOTAL_BLOCKS, 512, 0, stream>>>(L, R, I_enh, M, ws);
  final_kernel<<<1, 256, 0, stream>>>(ws, out);
}